// Round 10
// baseline (193.762 us; speedup 1.0000x reference)
//
#include <hip/hip_runtime.h>
#include <hip/hip_bf16.h>

#define B_  32
#define HW_ 4096
#define C_  256
#define S72 72                 // row stride in ushorts: [hi 0..31 | lo 32..63 | pad 64..71], 144B rows
#define BUF_ (128 * S72)       // one buffer = 128 rows

using bf16x8 = __attribute__((ext_vector_type(8))) short;
using f32x4  = __attribute__((ext_vector_type(4))) float;
using u32x4  = __attribute__((ext_vector_type(4))) uint;

__device__ __forceinline__ ushort f2bf_rn(float x) {
    uint u = __builtin_bit_cast(uint, x);
    u += 0x7FFFu + ((u >> 16) & 1u);
    return (ushort)(u >> 16);
}
__device__ __forceinline__ uint pk_bf2(float a, float b) {   // RN pack (K2 only)
    return ((uint)f2bf_rn(b) << 16) | (uint)f2bf_rn(a);
}
// 1-instr RTZ pack of two floats' top-16 bits: {bf16_rtz(x1), bf16_rtz(x0)}
__device__ __forceinline__ uint pk_rtz(float x0, float x1) {
    return __builtin_amdgcn_perm(__builtin_bit_cast(uint, x1),
                                 __builtin_bit_cast(uint, x0), 0x07060302u);
}
// RTZ split: x = hi + lo, hi = truncate-to-bf16, |lo| <= 2^-8|x|
__device__ __forceinline__ void split2_rtz(float x0, float x1, uint& hi2, uint& lo2) {
    uint u0 = __builtin_bit_cast(uint, x0), u1 = __builtin_bit_cast(uint, x1);
    hi2 = __builtin_amdgcn_perm(u1, u0, 0x07060302u);
    float h0 = __builtin_bit_cast(float, u0 & 0xFFFF0000u);
    float h1 = __builtin_bit_cast(float, u1 & 0xFFFF0000u);
    lo2 = pk_rtz(x0 - h0, x1 - h1);
}

// ---------------------------------------------------------------------------
// K1: scores[b,q,k] = sum_hw Q[b,hw,q]*K[b,hw,k] via 3-term bf16 RTZ split.
// Tile 128(q) x 128(k), split-K=8, 256-thread blocks (4 waves, 2x2 of 64x64).
// K3-style schedule: double-buffered LDS, ONE barrier per K-step:
//   issue loads(t+1) -> MFMA(t) from buf[t&1] -> convert+store(t+1) -> sync.
// LDS rows interleave hi|lo (stride 72 ushorts = 144B, 16B-aligned b128 ops,
// read quads (r+g)%8 cycle all 8 bank-quads -> conflict-free).
// 73.7KB/block -> 2 blocks/CU (two independent barrier groups per SIMD).
// grid 1024 = b(32) * tm(2) * tn(2) * s(8).
// ---------------------------------------------------------------------------
__global__ __launch_bounds__(256, 2) void scores_kernel(const float* __restrict__ qg,
                                                        const float* __restrict__ kg,
                                                        float* __restrict__ scores) {
    int x  = blockIdx.x;
    int s  = x & 7;
    int tn = (x >> 3) & 1;
    int tm = (x >> 4) & 1;
    int b  = x >> 5;

    __shared__ __align__(16) ushort QHL[2 * BUF_], KHL[2 * BUF_];

    int tid = threadIdx.x, lane = tid & 63, w = tid >> 6;
    int m0 = (w >> 1) * 64;
    int n0 = (w & 1) * 64;
    int g = lane >> 4, r16 = lane & 15;

    int cc = tid & 127;          // staging channel/row (same for Q and K)
    int hh = (tid >> 7) * 16;    // hw offset {0,16}, 16 values per thread

    const float* qcol = qg + (size_t)b * HW_ * C_ + tm * 128 + cc;
    const float* kcol = kg + (size_t)b * HW_ * C_ + tn * 128 + cc;

    f32x4 acc[4][4];
#pragma unroll
    for (int i = 0; i < 4; ++i)
#pragma unroll
        for (int j = 0; j < 4; ++j) acc[i][j] = (f32x4){0.f, 0.f, 0.f, 0.f};

    float qv[16], kv[16];

#define LOAD_QK(itv) {                                                         \
        int hw0 = s * 512 + (itv) * 32 + hh;                                   \
        const float* qp = qcol + (size_t)hw0 * C_;                             \
        const float* kp = kcol + (size_t)hw0 * C_;                             \
        _Pragma("unroll")                                                      \
        for (int j = 0; j < 16; ++j) qv[j] = qp[(size_t)j * C_];               \
        _Pragma("unroll")                                                      \
        for (int j = 0; j < 16; ++j) kv[j] = kp[(size_t)j * C_];               \
    }

#define CONVERT_STORE(ofs) {                                                   \
        uint h[8], l[8];                                                       \
        _Pragma("unroll")                                                      \
        for (int p = 0; p < 8; ++p) split2_rtz(qv[2 * p], qv[2 * p + 1], h[p], l[p]); \
        int bh = (ofs) + cc * S72 + hh;                                        \
        *reinterpret_cast<u32x4*>(&QHL[bh])      = (u32x4){h[0], h[1], h[2], h[3]}; \
        *reinterpret_cast<u32x4*>(&QHL[bh + 8])  = (u32x4){h[4], h[5], h[6], h[7]}; \
        *reinterpret_cast<u32x4*>(&QHL[bh + 32]) = (u32x4){l[0], l[1], l[2], l[3]}; \
        *reinterpret_cast<u32x4*>(&QHL[bh + 40]) = (u32x4){l[4], l[5], l[6], l[7]}; \
        _Pragma("unroll")                                                      \
        for (int p = 0; p < 8; ++p) split2_rtz(kv[2 * p], kv[2 * p + 1], h[p], l[p]); \
        *reinterpret_cast<u32x4*>(&KHL[bh])      = (u32x4){h[0], h[1], h[2], h[3]}; \
        *reinterpret_cast<u32x4*>(&KHL[bh + 8])  = (u32x4){h[4], h[5], h[6], h[7]}; \
        *reinterpret_cast<u32x4*>(&KHL[bh + 32]) = (u32x4){l[0], l[1], l[2], l[3]}; \
        *reinterpret_cast<u32x4*>(&KHL[bh + 40]) = (u32x4){l[4], l[5], l[6], l[7]}; \
    }

#define MFMA_PHASE(ofs) {                                                      \
        __builtin_amdgcn_s_setprio(1);                                         \
        bf16x8 ahi[4], alo[4];                                                 \
        _Pragma("unroll")                                                      \
        for (int mi = 0; mi < 4; ++mi) {                                       \
            int ro = (ofs) + (m0 + mi * 16 + r16) * S72 + g * 8;               \
            ahi[mi] = *reinterpret_cast<const bf16x8*>(&QHL[ro]);              \
            alo[mi] = *reinterpret_cast<const bf16x8*>(&QHL[ro + 32]);         \
        }                                                                      \
        _Pragma("unroll")                                                      \
        for (int ni = 0; ni < 4; ++ni) {                                       \
            int ro = (ofs) + (n0 + ni * 16 + r16) * S72 + g * 8;               \
            bf16x8 bhi = *reinterpret_cast<const bf16x8*>(&KHL[ro]);           \
            bf16x8 blo = *reinterpret_cast<const bf16x8*>(&KHL[ro + 32]);      \
            _Pragma("unroll")                                                  \
            for (int mi = 0; mi < 4; ++mi) {                                   \
                acc[mi][ni] = __builtin_amdgcn_mfma_f32_16x16x32_bf16(ahi[mi], bhi, acc[mi][ni], 0, 0, 0); \
                acc[mi][ni] = __builtin_amdgcn_mfma_f32_16x16x32_bf16(ahi[mi], blo, acc[mi][ni], 0, 0, 0); \
                acc[mi][ni] = __builtin_amdgcn_mfma_f32_16x16x32_bf16(alo[mi], bhi, acc[mi][ni], 0, 0, 0); \
            }                                                                  \
        }                                                                      \
        __builtin_amdgcn_s_setprio(0);                                         \
    }

    // prologue: stage iter 0 into buf 0
    LOAD_QK(0);
    CONVERT_STORE(0);
    __syncthreads();

#pragma unroll 2
    for (int it = 0; it < 16; ++it) {
        int cofs = (it & 1) * BUF_;
        int nofs = ((it + 1) & 1) * BUF_;
        if (it < 15) LOAD_QK(it + 1);     // issue early; latency hides under MFMA
        MFMA_PHASE(cofs);
        if (it < 15) {
            CONVERT_STORE(nofs);          // other buffer: no WAR with current reads
            __syncthreads();              // single barrier per K-step
        }
    }

    // epilogue: C/D layout col=lane&15, row=(lane>>4)*4+reg (m89-verified)
#pragma unroll
    for (int mi = 0; mi < 4; ++mi)
#pragma unroll
        for (int ni = 0; ni < 4; ++ni)
#pragma unroll
            for (int r = 0; r < 4; ++r) {
                int qrow = tm * 128 + m0 + mi * 16 + g * 4 + r;
                int kc   = tn * 128 + n0 + ni * 16 + r16;
                atomicAdd(&scores[((size_t)b * 256 + qrow) * 256 + kc], acc[mi][ni][r]);
            }
#undef MFMA_PHASE
#undef CONVERT_STORE
#undef LOAD_QK
}

// ---------------------------------------------------------------------------
// K2: row softmax over k (256), one wave per row; attn stored as bf16 (RN).
// ---------------------------------------------------------------------------
__global__ __launch_bounds__(256) void softmax_kernel(const float* __restrict__ scores,
                                                      ushort* __restrict__ attn) {
    int wid  = blockIdx.x * 4 + (threadIdx.x >> 6);
    int lane = threadIdx.x & 63;
    const float4 v = *reinterpret_cast<const float4*>(scores + (size_t)wid * 256 + lane * 4);
    float m = fmaxf(fmaxf(v.x, v.y), fmaxf(v.z, v.w));
#pragma unroll
    for (int off = 32; off; off >>= 1) m = fmaxf(m, __shfl_xor(m, off, 64));
    float e0 = __expf(v.x - m), e1 = __expf(v.y - m), e2 = __expf(v.z - m), e3 = __expf(v.w - m);
    float ssum = e0 + e1 + e2 + e3;
#pragma unroll
    for (int off = 32; off; off >>= 1) ssum += __shfl_xor(ssum, off, 64);
    float inv = 1.0f / ssum;
    uint2 o;
    o.x = pk_bf2(e0 * inv, e1 * inv);
    o.y = pk_bf2(e2 * inv, e3 * inv);
    *reinterpret_cast<uint2*>(attn + (size_t)wid * 256 + lane * 4) = o;
}

// ---------------------------------------------------------------------------
// K3: out[b,q,hw] = sum_k attn[b,q,k] * V[b,hw,k].  M=256 x N=64 tile, K=256
// in 8 steps of 32. V tile staged ONCE per block into LDS (fp32, XOR-swizzled
// 16B slots), double-buffered with T14 async-stage: issue ks+1 loads ->
// compute ks from LDS -> write ks+1 -> barrier. Waves read shared V from LDS.
// grid 2048 = b(32) * hw-tile(64); block 256 (4 waves, each 64q x 64hw).
// ---------------------------------------------------------------------------
__global__ __launch_bounds__(256, 4) void pv_kernel(const ushort* __restrict__ attn,
                                                    const float* __restrict__ vg,
                                                    float* __restrict__ out) {
    int b   = blockIdx.x >> 6;
    int hw0 = (blockIdx.x & 63) * 64;
    int tid = threadIdx.x, lane = tid & 63, w = tid >> 6;
    int m0  = w * 64;
    int g   = lane >> 4, r16 = lane & 15;

    __shared__ __align__(16) float Vt[2 * 64 * 32];   // [buf][hw 64][k 32], swizzled

    int srow = tid >> 2;
    int sslot = (tid & 3) * 2;
    int wi0 = srow * 32 + ((sslot ^ (srow & 7)) * 4);
    int wi1 = srow * 32 + (((sslot + 1) ^ (srow & 7)) * 4);
    const float* vstage = vg + ((size_t)(b * HW_ + hw0 + srow)) * C_ + sslot * 4;

    const ushort* abase = attn + (size_t)b * 256 * 256 + g * 8;

    f32x4 acc[4][4];
#pragma unroll
    for (int i = 0; i < 4; ++i)
#pragma unroll
        for (int j = 0; j < 4; ++j) acc[i][j] = (f32x4){0.f, 0.f, 0.f, 0.f};

    {
        f32x4 p0 = *reinterpret_cast<const f32x4*>(vstage);
        f32x4 p1 = *reinterpret_cast<const f32x4*>(vstage + 4);
        *reinterpret_cast<f32x4*>(&Vt[wi0]) = p0;
        *reinterpret_cast<f32x4*>(&Vt[wi1]) = p1;
    }
    __syncthreads();

    for (int p = 0; p < 8; ++p) {
        float* rbuf = &Vt[(p & 1) * 64 * 32];
        float* wbuf = &Vt[((p + 1) & 1) * 64 * 32];

        f32x4 n0v, n1v;
        if (p < 7) {
            n0v = *reinterpret_cast<const f32x4*>(vstage + (p + 1) * 32);
            n1v = *reinterpret_cast<const f32x4*>(vstage + (p + 1) * 32 + 4);
        }

        int k0 = p * 32;
        bf16x8 a[4];
#pragma unroll
        for (int mi = 0; mi < 4; ++mi)
            a[mi] = *reinterpret_cast<const bf16x8*>(abase + (size_t)(m0 + mi * 16 + r16) * 256 + k0);

#pragma unroll
        for (int ni = 0; ni < 4; ++ni) {
            int row = ni * 16 + r16, key = row & 7;
            f32x4 f0 = *reinterpret_cast<const f32x4*>(&rbuf[row * 32 + (((2 * g)     ^ key) * 4)]);
            f32x4 f1 = *reinterpret_cast<const f32x4*>(&rbuf[row * 32 + (((2 * g + 1) ^ key) * 4)]);
            bf16x8 bf = __builtin_bit_cast(bf16x8, (u32x4){
                pk_rtz(f0[0], f0[1]), pk_rtz(f0[2], f0[3]),
                pk_rtz(f1[0], f1[1]), pk_rtz(f1[2], f1[3])});
#pragma unroll
            for (int mi = 0; mi < 4; ++mi)
                acc[mi][ni] = __builtin_amdgcn_mfma_f32_16x16x32_bf16(a[mi], bf, acc[mi][ni], 0, 0, 0);
        }

        if (p < 7) {
            *reinterpret_cast<f32x4*>(&wbuf[wi0]) = n0v;
            *reinterpret_cast<f32x4*>(&wbuf[wi1]) = n1v;
            __syncthreads();
        }
    }

#pragma unroll
    for (int mi = 0; mi < 4; ++mi)
#pragma unroll
        for (int ni = 0; ni < 4; ++ni)
#pragma unroll
            for (int r = 0; r < 4; ++r) {
                int qrow = m0 + mi * 16 + g * 4 + r;
                int hw   = hw0 + ni * 16 + r16;
                out[((size_t)b * 256 + qrow) * 4096 + hw] = acc[mi][ni][r];
            }
}

extern "C" void kernel_launch(void* const* d_in, const int* in_sizes, int n_in,
                              void* d_out, int out_size, void* d_ws, size_t ws_size,
                              hipStream_t stream) {
    const float* q = (const float*)d_in[0];
    const float* k = (const float*)d_in[1];
    const float* v = (const float*)d_in[2];
    float* out = (float*)d_out;

    float*  scores = (float*)d_ws;
    ushort* attn   = (ushort*)((char*)d_ws + (size_t)B_ * 256 * 256 * 4);

    (void)hipMemsetAsync(d_ws, 0, (size_t)B_ * 256 * 256 * 4, stream);
    scores_kernel<<<1024, 256, 0, stream>>>(q, k, scores);
    softmax_kernel<<<2048, 256, 0, stream>>>(scores, attn);
    pv_kernel<<<2048, 256, 0, stream>>>(attn, v, out);
}

// Round 12
// 181.828 us; speedup vs baseline: 1.0656x; 1.0656x over previous
//
#include <hip/hip_runtime.h>
#include <hip/hip_bf16.h>

#define B_  32
#define HW_ 4096
#define C_  256
#define S_LDS 40   // LDS row stride in ushorts (80B): 16B-aligned rows, b128 r/w 2-way banks (free)

using bf16x8 = __attribute__((ext_vector_type(8))) short;
using f32x4  = __attribute__((ext_vector_type(4))) float;
using u32x4  = __attribute__((ext_vector_type(4))) uint;

__device__ __forceinline__ ushort f2bf_rn(float x) {
    uint u = __builtin_bit_cast(uint, x);
    u += 0x7FFFu + ((u >> 16) & 1u);
    return (ushort)(u >> 16);
}
__device__ __forceinline__ uint pk_bf2(float a, float b) {   // RN pack (K2 only)
    return ((uint)f2bf_rn(b) << 16) | (uint)f2bf_rn(a);
}
// 1-instr RTZ pack of two floats' top-16 bits: {bf16_rtz(x1), bf16_rtz(x0)}
__device__ __forceinline__ uint pk_rtz(float x0, float x1) {
    return __builtin_amdgcn_perm(__builtin_bit_cast(uint, x1),
                                 __builtin_bit_cast(uint, x0), 0x07060302u);
}
// RTZ split: x = hi + lo, hi = truncate-to-bf16, |lo| <= 2^-8|x|
__device__ __forceinline__ void split2_rtz(float x0, float x1, uint& hi2, uint& lo2) {
    uint u0 = __builtin_bit_cast(uint, x0), u1 = __builtin_bit_cast(uint, x1);
    hi2 = __builtin_amdgcn_perm(u1, u0, 0x07060302u);
    float h0 = __builtin_bit_cast(float, u0 & 0xFFFF0000u);
    float h1 = __builtin_bit_cast(float, u1 & 0xFFFF0000u);
    lo2 = pk_rtz(x0 - h0, x1 - h1);
}

// ---------------------------------------------------------------------------
// K1: scores[b,q,k] = sum_hw Q[b,hw,q]*K[b,hw,k] via 3-term bf16 RTZ split
// (PROVEN numerics: absmax 0.0625). R4's fastest-measured structure (tile
// 128q x 64k, reg-prefetch double-buffer, 2-barrier step, 30.7KB LDS) with
// split-K=8 -> grid 2048: 5 resident blocks/CU (LDS-limited), 20 waves/CU,
// 5 INDEPENDENT barrier groups per CU to cross-cover load/barrier latency.
// grid 2048 = b(32) * tm(2) * tn(4) * s(8); block 256 (4 waves, 2x2 of 64x32).
// ---------------------------------------------------------------------------
__global__ __launch_bounds__(256, 4) void scores_kernel(const float* __restrict__ qg,
                                                        const float* __restrict__ kg,
                                                        float* __restrict__ scores) {
    int x  = blockIdx.x;
    int s  = x & 7;
    int tn = (x >> 3) & 3;
    int tm = (x >> 5) & 1;
    int b  = x >> 6;

    __shared__ __align__(16) ushort Qhi[128 * S_LDS], Qlo[128 * S_LDS];
    __shared__ __align__(16) ushort Khi[64 * S_LDS],  Klo[64 * S_LDS];

    int tid = threadIdx.x, lane = tid & 63, w = tid >> 6;
    int m0 = (w >> 1) * 64;     // wave q-offset (2x2 wave grid over 128x64)
    int n0 = (w & 1) * 32;      // wave k-offset
    int g = lane >> 4, r16 = lane & 15;

    int cq = tid & 127;          // staging: q-channel owned by this thread
    int hq = (tid >> 7) * 16;    // 16 hw values
    int ck = tid & 63;           // staging: k-channel
    int hk = (tid >> 6) * 8;     // 8 hw values

    const float* qcol = qg + (size_t)b * HW_ * C_ + tm * 128 + cq;
    const float* kcol = kg + (size_t)b * HW_ * C_ + tn * 64 + ck;

    f32x4 acc[4][2];
#pragma unroll
    for (int i = 0; i < 4; ++i)
#pragma unroll
        for (int j = 0; j < 2; ++j) acc[i][j] = (f32x4){0.f, 0.f, 0.f, 0.f};

#define LOAD_QK(qr, kr, itv) {                                                 \
        int hw0 = s * 512 + (itv) * 32;                                        \
        const float* qp = qcol + (size_t)(hw0 + hq) * C_;                      \
        _Pragma("unroll")                                                      \
        for (int j = 0; j < 16; ++j) qr[j] = qp[(size_t)j * C_];               \
        const float* kp = kcol + (size_t)(hw0 + hk) * C_;                      \
        _Pragma("unroll")                                                      \
        for (int j = 0; j < 8; ++j) kr[j] = kp[(size_t)j * C_];                \
    }

#define CONVERT_STORE(qr, kr) {                                                \
        uint qh[8], ql[8];                                                     \
        _Pragma("unroll")                                                      \
        for (int p = 0; p < 8; ++p) split2_rtz(qr[2*p], qr[2*p+1], qh[p], ql[p]); \
        int qb_ = cq * S_LDS + hq;                                             \
        *reinterpret_cast<u32x4*>(&Qhi[qb_])     = (u32x4){qh[0], qh[1], qh[2], qh[3]}; \
        *reinterpret_cast<u32x4*>(&Qhi[qb_ + 8]) = (u32x4){qh[4], qh[5], qh[6], qh[7]}; \
        *reinterpret_cast<u32x4*>(&Qlo[qb_])     = (u32x4){ql[0], ql[1], ql[2], ql[3]}; \
        *reinterpret_cast<u32x4*>(&Qlo[qb_ + 8]) = (u32x4){ql[4], ql[5], ql[6], ql[7]}; \
        uint kh[4], kl[4];                                                     \
        _Pragma("unroll")                                                      \
        for (int p = 0; p < 4; ++p) split2_rtz(kr[2*p], kr[2*p+1], kh[p], kl[p]); \
        int kb_ = ck * S_LDS + hk;                                             \
        *reinterpret_cast<u32x4*>(&Khi[kb_]) = (u32x4){kh[0], kh[1], kh[2], kh[3]}; \
        *reinterpret_cast<u32x4*>(&Klo[kb_]) = (u32x4){kl[0], kl[1], kl[2], kl[3]}; \
    }

#define MFMA_PHASE() {                                                         \
        __builtin_amdgcn_s_setprio(1);                                         \
        bf16x8 ahi[4], alo[4];                                                 \
        _Pragma("unroll")                                                      \
        for (int mi = 0; mi < 4; ++mi) {                                       \
            int off = (m0 + mi * 16 + r16) * S_LDS + g * 8;                    \
            ahi[mi] = *reinterpret_cast<const bf16x8*>(&Qhi[off]);             \
            alo[mi] = *reinterpret_cast<const bf16x8*>(&Qlo[off]);             \
        }                                                                      \
        _Pragma("unroll")                                                      \
        for (int ni = 0; ni < 2; ++ni) {                                       \
            int off = (n0 + ni * 16 + r16) * S_LDS + g * 8;                    \
            bf16x8 bhi = *reinterpret_cast<const bf16x8*>(&Khi[off]);          \
            bf16x8 blo = *reinterpret_cast<const bf16x8*>(&Klo[off]);          \
            _Pragma("unroll")                                                  \
            for (int mi = 0; mi < 4; ++mi) {                                   \
                acc[mi][ni] = __builtin_amdgcn_mfma_f32_16x16x32_bf16(ahi[mi], bhi, acc[mi][ni], 0, 0, 0); \
                acc[mi][ni] = __builtin_amdgcn_mfma_f32_16x16x32_bf16(ahi[mi], blo, acc[mi][ni], 0, 0, 0); \
                acc[mi][ni] = __builtin_amdgcn_mfma_f32_16x16x32_bf16(alo[mi], bhi, acc[mi][ni], 0, 0, 0); \
            }                                                                  \
        }                                                                      \
        __builtin_amdgcn_s_setprio(0);                                         \
    }

#define STEP(qc, kc, qn, kn, itv, doload) {                                    \
        if (doload) LOAD_QK(qn, kn, (itv) + 1);                                \
        __syncthreads();                                                       \
        CONVERT_STORE(qc, kc);                                                 \
        __syncthreads();                                                       \
        MFMA_PHASE();                                                          \
    }

    float qa[16], ka[8], qb[16], kb[8];
    LOAD_QK(qa, ka, 0);
    for (int p = 0; p < 8; ++p) {
        STEP(qa, ka, qb, kb, 2 * p, true);        // prefetch iter 2p+1 (<=15)
        STEP(qb, kb, qa, ka, 2 * p + 1, p < 7);   // prefetch iter 2p+2 (<=14)
    }

    // epilogue: C/D layout col=lane&15, row=(lane>>4)*4+reg (m89-verified)
#pragma unroll
    for (int mi = 0; mi < 4; ++mi)
#pragma unroll
        for (int ni = 0; ni < 2; ++ni)
#pragma unroll
            for (int r = 0; r < 4; ++r) {
                int qrow = tm * 128 + m0 + mi * 16 + g * 4 + r;
                int kc   = tn * 64 + n0 + ni * 16 + r16;
                atomicAdd(&scores[((size_t)b * 256 + qrow) * 256 + kc], acc[mi][ni][r]);
            }
#undef STEP
#undef MFMA_PHASE
#undef CONVERT_STORE
#undef LOAD_QK
}

// ---------------------------------------------------------------------------
// K2: row softmax over k (256), one wave per row; attn stored as bf16 (RN).
// ---------------------------------------------------------------------------
__global__ __launch_bounds__(256) void softmax_kernel(const float* __restrict__ scores,
                                                      ushort* __restrict__ attn) {
    int wid  = blockIdx.x * 4 + (threadIdx.x >> 6);
    int lane = threadIdx.x & 63;
    const float4 v = *reinterpret_cast<const float4*>(scores + (size_t)wid * 256 + lane * 4);
    float m = fmaxf(fmaxf(v.x, v.y), fmaxf(v.z, v.w));
#pragma unroll
    for (int off = 32; off; off >>= 1) m = fmaxf(m, __shfl_xor(m, off, 64));
    float e0 = __expf(v.x - m), e1 = __expf(v.y - m), e2 = __expf(v.z - m), e3 = __expf(v.w - m);
    float ssum = e0 + e1 + e2 + e3;
#pragma unroll
    for (int off = 32; off; off >>= 1) ssum += __shfl_xor(ssum, off, 64);
    float inv = 1.0f / ssum;
    uint2 o;
    o.x = pk_bf2(e0 * inv, e1 * inv);
    o.y = pk_bf2(e2 * inv, e3 * inv);
    *reinterpret_cast<uint2*>(attn + (size_t)wid * 256 + lane * 4) = o;
}

// ---------------------------------------------------------------------------
// K3: out[b,q,hw] = sum_k attn[b,q,k] * V[b,hw,k].  M=256 x N=64 tile, K=256
// in 8 steps of 32. V tile staged ONCE per block into LDS (fp32, XOR-swizzled
// 16B slots), double-buffered with T14 async-stage: issue ks+1 loads ->
// compute ks from LDS -> write ks+1 -> barrier. Waves read shared V from LDS.
// grid 2048 = b(32) * hw-tile(64); block 256 (4 waves, each 64q x 64hw).
// (3x validated: R6/R8/R10, absmax 0.0625)
// ---------------------------------------------------------------------------
__global__ __launch_bounds__(256, 4) void pv_kernel(const ushort* __restrict__ attn,
                                                    const float* __restrict__ vg,
                                                    float* __restrict__ out) {
    int b   = blockIdx.x >> 6;
    int hw0 = (blockIdx.x & 63) * 64;
    int tid = threadIdx.x, lane = tid & 63, w = tid >> 6;
    int m0  = w * 64;
    int g   = lane >> 4, r16 = lane & 15;

    __shared__ __align__(16) float Vt[2 * 64 * 32];   // [buf][hw 64][k 32], swizzled

    int srow = tid >> 2;
    int sslot = (tid & 3) * 2;
    int wi0 = srow * 32 + ((sslot ^ (srow & 7)) * 4);
    int wi1 = srow * 32 + (((sslot + 1) ^ (srow & 7)) * 4);
    const float* vstage = vg + ((size_t)(b * HW_ + hw0 + srow)) * C_ + sslot * 4;

    const ushort* abase = attn + (size_t)b * 256 * 256 + g * 8;

    f32x4 acc[4][4];
#pragma unroll
    for (int i = 0; i < 4; ++i)
#pragma unroll
        for (int j = 0; j < 4; ++j) acc[i][j] = (f32x4){0.f, 0.f, 0.f, 0.f};

    {
        f32x4 p0 = *reinterpret_cast<const f32x4*>(vstage);
        f32x4 p1 = *reinterpret_cast<const f32x4*>(vstage + 4);
        *reinterpret_cast<f32x4*>(&Vt[wi0]) = p0;
        *reinterpret_cast<f32x4*>(&Vt[wi1]) = p1;
    }
    __syncthreads();

    for (int p = 0; p < 8; ++p) {
        float* rbuf = &Vt[(p & 1) * 64 * 32];
        float* wbuf = &Vt[((p + 1) & 1) * 64 * 32];

        f32x4 n0v, n1v;
        if (p < 7) {
            n0v = *reinterpret_cast<const f32x4*>(vstage + (p + 1) * 32);
            n1v = *reinterpret_cast<const f32x4*>(vstage + (p + 1) * 32 + 4);
        }

        int k0 = p * 32;
        bf16x8 a[4];
#pragma unroll
        for (int mi = 0; mi < 4; ++mi)
            a[mi] = *reinterpret_cast<const bf16x8*>(abase + (size_t)(m0 + mi * 16 + r16) * 256 + k0);

#pragma unroll
        for (int ni = 0; ni < 4; ++ni) {
            int row = ni * 16 + r16, key = row & 7;
            f32x4 f0 = *reinterpret_cast<const f32x4*>(&rbuf[row * 32 + (((2 * g)     ^ key) * 4)]);
            f32x4 f1 = *reinterpret_cast<const f32x4*>(&rbuf[row * 32 + (((2 * g + 1) ^ key) * 4)]);
            bf16x8 bf = __builtin_bit_cast(bf16x8, (u32x4){
                pk_rtz(f0[0], f0[1]), pk_rtz(f0[2], f0[3]),
                pk_rtz(f1[0], f1[1]), pk_rtz(f1[2], f1[3])});
#pragma unroll
            for (int mi = 0; mi < 4; ++mi)
                acc[mi][ni] = __builtin_amdgcn_mfma_f32_16x16x32_bf16(a[mi], bf, acc[mi][ni], 0, 0, 0);
        }

        if (p < 7) {
            *reinterpret_cast<f32x4*>(&wbuf[wi0]) = n0v;
            *reinterpret_cast<f32x4*>(&wbuf[wi1]) = n1v;
            __syncthreads();
        }
    }

#pragma unroll
    for (int mi = 0; mi < 4; ++mi)
#pragma unroll
        for (int ni = 0; ni < 4; ++ni)
#pragma unroll
            for (int r = 0; r < 4; ++r) {
                int qrow = m0 + mi * 16 + g * 4 + r;
                int hw   = hw0 + ni * 16 + r16;
                out[((size_t)b * 256 + qrow) * 4096 + hw] = acc[mi][ni][r];
            }
}

extern "C" void kernel_launch(void* const* d_in, const int* in_sizes, int n_in,
                              void* d_out, int out_size, void* d_ws, size_t ws_size,
                              hipStream_t stream) {
    const float* q = (const float*)d_in[0];
    const float* k = (const float*)d_in[1];
    const float* v = (const float*)d_in[2];
    float* out = (float*)d_out;

    float*  scores = (float*)d_ws;
    ushort* attn   = (ushort*)((char*)d_ws + (size_t)B_ * 256 * 256 * 4);

    (void)hipMemsetAsync(d_ws, 0, (size_t)B_ * 256 * 256 * 4, stream);
    scores_kernel<<<2048, 256, 0, stream>>>(q, k, scores);
    softmax_kernel<<<2048, 256, 0, stream>>>(scores, attn);
    pv_kernel<<<2048, 256, 0, stream>>>(attn, v, out);
}

// Round 13
// 174.383 us; speedup vs baseline: 1.1111x; 1.0427x over previous
//
#include <hip/hip_runtime.h>
#include <hip/hip_bf16.h>

#define B_  32
#define HW_ 4096
#define C_  256
#define S_LDS 40   // LDS row stride in ushorts (80B): 16B-aligned rows, b128 r/w 2-way banks (free)

using bf16x8 = __attribute__((ext_vector_type(8))) short;
using f32x4  = __attribute__((ext_vector_type(4))) float;
using u32x4  = __attribute__((ext_vector_type(4))) uint;

__device__ __forceinline__ ushort f2bf_rn(float x) {
    uint u = __builtin_bit_cast(uint, x);
    u += 0x7FFFu + ((u >> 16) & 1u);
    return (ushort)(u >> 16);
}
__device__ __forceinline__ uint pk_bf2(float a, float b) {   // RN pack (K2 only)
    return ((uint)f2bf_rn(b) << 16) | (uint)f2bf_rn(a);
}
// 1-instr RTZ pack of two floats' top-16 bits: {bf16_rtz(x1), bf16_rtz(x0)}
__device__ __forceinline__ uint pk_rtz(float x0, float x1) {
    return __builtin_amdgcn_perm(__builtin_bit_cast(uint, x1),
                                 __builtin_bit_cast(uint, x0), 0x07060302u);
}
// RTZ split: x = hi + lo, hi = truncate-to-bf16, |lo| <= 2^-8|x|
__device__ __forceinline__ void split2_rtz(float x0, float x1, uint& hi2, uint& lo2) {
    uint u0 = __builtin_bit_cast(uint, x0), u1 = __builtin_bit_cast(uint, x1);
    hi2 = __builtin_amdgcn_perm(u1, u0, 0x07060302u);
    float h0 = __builtin_bit_cast(float, u0 & 0xFFFF0000u);
    float h1 = __builtin_bit_cast(float, u1 & 0xFFFF0000u);
    lo2 = pk_rtz(x0 - h0, x1 - h1);
}

// ---------------------------------------------------------------------------
// K1: scores[b,q,k] = sum_hw Q[b,hw,q]*K[b,hw,k] via 3-term bf16 RTZ split
// (proven numerics, absmax 0.0625). R4 structure (fastest measured): tile
// 128q x 64k, split-K=4, reg-prefetch double-buffer, 2-barrier step.
// NEW: no atomics. Each split-K slice s writes its own fp32 partial slab
// (plain coalesced stores); K2 sums slabs. Rationale: WRITE_SIZE proved
// device-scope fp32 atomicAdd writes through to HBM (memory-side RMW,
// 64 MB @ sK=8) - ~20us of pure atomic traffic eliminated.
// slabStride==0 => atomic fallback into single slab (ws too small).
// grid 1024 = b(32) * tm(2) * tn(4) * s(4); block 256 (4 waves, 2x2 of 64x32).
// ---------------------------------------------------------------------------
__global__ __launch_bounds__(256, 4) void scores_kernel(const float* __restrict__ qg,
                                                        const float* __restrict__ kg,
                                                        float* __restrict__ dst,
                                                        long slabStride) {
    int x  = blockIdx.x;
    int s  = x & 3;
    int tn = (x >> 2) & 3;
    int tm = (x >> 4) & 1;
    int b  = x >> 5;

    __shared__ __align__(16) ushort Qhi[128 * S_LDS], Qlo[128 * S_LDS];
    __shared__ __align__(16) ushort Khi[64 * S_LDS],  Klo[64 * S_LDS];

    int tid = threadIdx.x, lane = tid & 63, w = tid >> 6;
    int m0 = (w >> 1) * 64;     // wave q-offset (2x2 wave grid over 128x64)
    int n0 = (w & 1) * 32;      // wave k-offset
    int g = lane >> 4, r16 = lane & 15;

    int cq = tid & 127;          // staging: q-channel owned by this thread
    int hq = (tid >> 7) * 16;    // 16 hw values
    int ck = tid & 63;           // staging: k-channel
    int hk = (tid >> 6) * 8;     // 8 hw values

    const float* qcol = qg + (size_t)b * HW_ * C_ + tm * 128 + cq;
    const float* kcol = kg + (size_t)b * HW_ * C_ + tn * 64 + ck;

    f32x4 acc[4][2];
#pragma unroll
    for (int i = 0; i < 4; ++i)
#pragma unroll
        for (int j = 0; j < 2; ++j) acc[i][j] = (f32x4){0.f, 0.f, 0.f, 0.f};

#define LOAD_QK(qr, kr, itv) {                                                 \
        int hw0 = s * 1024 + (itv) * 32;                                       \
        const float* qp = qcol + (size_t)(hw0 + hq) * C_;                      \
        _Pragma("unroll")                                                      \
        for (int j = 0; j < 16; ++j) qr[j] = qp[(size_t)j * C_];               \
        const float* kp = kcol + (size_t)(hw0 + hk) * C_;                      \
        _Pragma("unroll")                                                      \
        for (int j = 0; j < 8; ++j) kr[j] = kp[(size_t)j * C_];                \
    }

#define CONVERT_STORE(qr, kr) {                                                \
        uint qh[8], ql[8];                                                     \
        _Pragma("unroll")                                                      \
        for (int p = 0; p < 8; ++p) split2_rtz(qr[2*p], qr[2*p+1], qh[p], ql[p]); \
        int qb_ = cq * S_LDS + hq;                                             \
        *reinterpret_cast<u32x4*>(&Qhi[qb_])     = (u32x4){qh[0], qh[1], qh[2], qh[3]}; \
        *reinterpret_cast<u32x4*>(&Qhi[qb_ + 8]) = (u32x4){qh[4], qh[5], qh[6], qh[7]}; \
        *reinterpret_cast<u32x4*>(&Qlo[qb_])     = (u32x4){ql[0], ql[1], ql[2], ql[3]}; \
        *reinterpret_cast<u32x4*>(&Qlo[qb_ + 8]) = (u32x4){ql[4], ql[5], ql[6], ql[7]}; \
        uint kh[4], kl[4];                                                     \
        _Pragma("unroll")                                                      \
        for (int p = 0; p < 4; ++p) split2_rtz(kr[2*p], kr[2*p+1], kh[p], kl[p]); \
        int kb_ = ck * S_LDS + hk;                                             \
        *reinterpret_cast<u32x4*>(&Khi[kb_]) = (u32x4){kh[0], kh[1], kh[2], kh[3]}; \
        *reinterpret_cast<u32x4*>(&Klo[kb_]) = (u32x4){kl[0], kl[1], kl[2], kl[3]}; \
    }

#define MFMA_PHASE() {                                                         \
        __builtin_amdgcn_s_setprio(1);                                         \
        bf16x8 ahi[4], alo[4];                                                 \
        _Pragma("unroll")                                                      \
        for (int mi = 0; mi < 4; ++mi) {                                       \
            int off = (m0 + mi * 16 + r16) * S_LDS + g * 8;                    \
            ahi[mi] = *reinterpret_cast<const bf16x8*>(&Qhi[off]);             \
            alo[mi] = *reinterpret_cast<const bf16x8*>(&Qlo[off]);             \
        }                                                                      \
        _Pragma("unroll")                                                      \
        for (int ni = 0; ni < 2; ++ni) {                                       \
            int off = (n0 + ni * 16 + r16) * S_LDS + g * 8;                    \
            bf16x8 bhi = *reinterpret_cast<const bf16x8*>(&Khi[off]);          \
            bf16x8 blo = *reinterpret_cast<const bf16x8*>(&Klo[off]);          \
            _Pragma("unroll")                                                  \
            for (int mi = 0; mi < 4; ++mi) {                                   \
                acc[mi][ni] = __builtin_amdgcn_mfma_f32_16x16x32_bf16(ahi[mi], bhi, acc[mi][ni], 0, 0, 0); \
                acc[mi][ni] = __builtin_amdgcn_mfma_f32_16x16x32_bf16(ahi[mi], blo, acc[mi][ni], 0, 0, 0); \
                acc[mi][ni] = __builtin_amdgcn_mfma_f32_16x16x32_bf16(alo[mi], bhi, acc[mi][ni], 0, 0, 0); \
            }                                                                  \
        }                                                                      \
        __builtin_amdgcn_s_setprio(0);                                         \
    }

#define STEP(qc, kc, qn, kn, itv, doload) {                                    \
        if (doload) LOAD_QK(qn, kn, (itv) + 1);                                \
        __syncthreads();                                                       \
        CONVERT_STORE(qc, kc);                                                 \
        __syncthreads();                                                       \
        MFMA_PHASE();                                                          \
    }

    float qa[16], ka[8], qb[16], kb[8];
    LOAD_QK(qa, ka, 0);
    for (int p = 0; p < 16; ++p) {
        STEP(qa, ka, qb, kb, 2 * p, true);         // prefetch 2p+1 (<=31 always)
        STEP(qb, kb, qa, ka, 2 * p + 1, p < 15);   // prefetch 2p+2 unless last
    }

    // epilogue: C/D layout col=lane&15, row=(lane>>4)*4+reg (m89-verified)
    float* base = dst + (size_t)s * slabStride;
#pragma unroll
    for (int mi = 0; mi < 4; ++mi)
#pragma unroll
        for (int ni = 0; ni < 2; ++ni)
#pragma unroll
            for (int r = 0; r < 4; ++r) {
                int qrow = tm * 128 + m0 + mi * 16 + g * 4 + r;
                int kc   = tn * 64 + n0 + ni * 16 + r16;
                float* p = base + ((size_t)b * 256 + qrow) * 256 + kc;
                if (slabStride) *p = acc[mi][ni][r];
                else            atomicAdd(p, acc[mi][ni][r]);
            }
#undef STEP
#undef MFMA_PHASE
#undef CONVERT_STORE
#undef LOAD_QK
}

// ---------------------------------------------------------------------------
// K2: sum nslab partial slabs, then row softmax over k (256); one wave/row.
// ---------------------------------------------------------------------------
__global__ __launch_bounds__(256) void softmax_kernel(const float* __restrict__ scores,
                                                      ushort* __restrict__ attn,
                                                      int nslab, long slabStride) {
    int wid  = blockIdx.x * 4 + (threadIdx.x >> 6);
    int lane = threadIdx.x & 63;
    const float* p0 = scores + (size_t)wid * 256 + lane * 4;
    float4 v = *reinterpret_cast<const float4*>(p0);
    for (int sl = 1; sl < nslab; ++sl) {
        const float4 t = *reinterpret_cast<const float4*>(p0 + (size_t)sl * slabStride);
        v.x += t.x; v.y += t.y; v.z += t.z; v.w += t.w;
    }
    float m = fmaxf(fmaxf(v.x, v.y), fmaxf(v.z, v.w));
#pragma unroll
    for (int off = 32; off; off >>= 1) m = fmaxf(m, __shfl_xor(m, off, 64));
    float e0 = __expf(v.x - m), e1 = __expf(v.y - m), e2 = __expf(v.z - m), e3 = __expf(v.w - m);
    float ssum = e0 + e1 + e2 + e3;
#pragma unroll
    for (int off = 32; off; off >>= 1) ssum += __shfl_xor(ssum, off, 64);
    float inv = 1.0f / ssum;
    uint2 o;
    o.x = pk_bf2(e0 * inv, e1 * inv);
    o.y = pk_bf2(e2 * inv, e3 * inv);
    *reinterpret_cast<uint2*>(attn + (size_t)wid * 256 + lane * 4) = o;
}

// ---------------------------------------------------------------------------
// K3: out[b,q,hw] = sum_k attn[b,q,k] * V[b,hw,k].  M=256 x N=64 tile, K=256
// in 8 steps of 32. V tile staged ONCE per block into LDS (fp32, XOR-swizzled
// 16B slots), double-buffered with T14 async-stage. (4x validated, 0.0625)
// grid 2048 = b(32) * hw-tile(64); block 256 (4 waves, each 64q x 64hw).
// ---------------------------------------------------------------------------
__global__ __launch_bounds__(256, 4) void pv_kernel(const ushort* __restrict__ attn,
                                                    const float* __restrict__ vg,
                                                    float* __restrict__ out) {
    int b   = blockIdx.x >> 6;
    int hw0 = (blockIdx.x & 63) * 64;
    int tid = threadIdx.x, lane = tid & 63, w = tid >> 6;
    int m0  = w * 64;
    int g   = lane >> 4, r16 = lane & 15;

    __shared__ __align__(16) float Vt[2 * 64 * 32];   // [buf][hw 64][k 32], swizzled

    int srow = tid >> 2;
    int sslot = (tid & 3) * 2;
    int wi0 = srow * 32 + ((sslot ^ (srow & 7)) * 4);
    int wi1 = srow * 32 + (((sslot + 1) ^ (srow & 7)) * 4);
    const float* vstage = vg + ((size_t)(b * HW_ + hw0 + srow)) * C_ + sslot * 4;

    const ushort* abase = attn + (size_t)b * 256 * 256 + g * 8;

    f32x4 acc[4][4];
#pragma unroll
    for (int i = 0; i < 4; ++i)
#pragma unroll
        for (int j = 0; j < 4; ++j) acc[i][j] = (f32x4){0.f, 0.f, 0.f, 0.f};

    {
        f32x4 p0 = *reinterpret_cast<const f32x4*>(vstage);
        f32x4 p1 = *reinterpret_cast<const f32x4*>(vstage + 4);
        *reinterpret_cast<f32x4*>(&Vt[wi0]) = p0;
        *reinterpret_cast<f32x4*>(&Vt[wi1]) = p1;
    }
    __syncthreads();

    for (int p = 0; p < 8; ++p) {
        float* rbuf = &Vt[(p & 1) * 64 * 32];
        float* wbuf = &Vt[((p + 1) & 1) * 64 * 32];

        f32x4 n0v, n1v;
        if (p < 7) {
            n0v = *reinterpret_cast<const f32x4*>(vstage + (p + 1) * 32);
            n1v = *reinterpret_cast<const f32x4*>(vstage + (p + 1) * 32 + 4);
        }

        int k0 = p * 32;
        bf16x8 a[4];
#pragma unroll
        for (int mi = 0; mi < 4; ++mi)
            a[mi] = *reinterpret_cast<const bf16x8*>(abase + (size_t)(m0 + mi * 16 + r16) * 256 + k0);

#pragma unroll
        for (int ni = 0; ni < 4; ++ni) {
            int row = ni * 16 + r16, key = row & 7;
            f32x4 f0 = *reinterpret_cast<const f32x4*>(&rbuf[row * 32 + (((2 * g)     ^ key) * 4)]);
            f32x4 f1 = *reinterpret_cast<const f32x4*>(&rbuf[row * 32 + (((2 * g + 1) ^ key) * 4)]);
            bf16x8 bf = __builtin_bit_cast(bf16x8, (u32x4){
                pk_rtz(f0[0], f0[1]), pk_rtz(f0[2], f0[3]),
                pk_rtz(f1[0], f1[1]), pk_rtz(f1[2], f1[3])});
#pragma unroll
            for (int mi = 0; mi < 4; ++mi)
                acc[mi][ni] = __builtin_amdgcn_mfma_f32_16x16x32_bf16(a[mi], bf, acc[mi][ni], 0, 0, 0);
        }

        if (p < 7) {
            *reinterpret_cast<f32x4*>(&wbuf[wi0]) = n0v;
            *reinterpret_cast<f32x4*>(&wbuf[wi1]) = n1v;
            __syncthreads();
        }
    }

#pragma unroll
    for (int mi = 0; mi < 4; ++mi)
#pragma unroll
        for (int ni = 0; ni < 4; ++ni)
#pragma unroll
            for (int r = 0; r < 4; ++r) {
                int qrow = m0 + mi * 16 + g * 4 + r;
                int hw   = hw0 + ni * 16 + r16;
                out[((size_t)b * 256 + qrow) * 4096 + hw] = acc[mi][ni][r];
            }
}

extern "C" void kernel_launch(void* const* d_in, const int* in_sizes, int n_in,
                              void* d_out, int out_size, void* d_ws, size_t ws_size,
                              hipStream_t stream) {
    const float* q = (const float*)d_in[0];
    const float* k = (const float*)d_in[1];
    const float* v = (const float*)d_in[2];
    float* out = (float*)d_out;

    const size_t slab = (size_t)B_ * 256 * 256;          // floats per slab (8 MB)
    const size_t needBytes = 4 * slab * 4 + slab * 2;    // 4 slabs + bf16 attn = 36 MB
    float* scores = (float*)d_ws;

    if (ws_size >= needBytes) {
        // partials path: no atomics, no memset
        ushort* attn = (ushort*)((char*)d_ws + 4 * slab * 4);
        scores_kernel<<<1024, 256, 0, stream>>>(q, k, scores, (long)slab);
        softmax_kernel<<<2048, 256, 0, stream>>>(scores, attn, 4, (long)slab);
        pv_kernel<<<2048, 256, 0, stream>>>(attn, v, out);
    } else {
        // atomic fallback (proven path)
        ushort* attn = (ushort*)((char*)d_ws + slab * 4);
        (void)hipMemsetAsync(d_ws, 0, slab * 4, stream);
        scores_kernel<<<1024, 256, 0, stream>>>(q, k, scores, 0L);
        softmax_kernel<<<2048, 256, 0, stream>>>(scores, attn, 1, 0L);
        pv_kernel<<<2048, 256, 0, stream>>>(attn, v, out);
    }
}